// Round 1
// baseline (699.850 us; speedup 1.0000x reference)
//
#include <hip/hip_runtime.h>
#include <math.h>

#define BN 8192
#define CN 1000
#define DN 128
#define INVT (1.0f/0.3f)

// ws layout in floats
#define F_FEATN  0          // 8192*128 = 1048576
#define F_XX     1048576    // 8192
#define F_MEANSN 1056768    // 128000
#define F_YY     1184768    // 1000
#define F_BOT    1185768    // 8192
#define F_POS    1193960    // 8192
#define F_CNT    1202152    // 1000 ints
#define F_CE     1203152    // 1
#define F_MG     1203153    // 1

// -------- row L2-normalize (one wave per row). raw_sq=1 -> sq = ||row||^2 (pre-norm),
// raw_sq=0 -> sq = sum of squares of the normalized row (matches reference XX). --------
__global__ void norm_rows(const float* __restrict__ src, float* __restrict__ dst,
                          float* __restrict__ sq, int nrows, int raw_sq) {
    int row = blockIdx.x * 4 + (threadIdx.x >> 6);
    if (row >= nrows) return;
    int lane = threadIdx.x & 63;
    float f0 = src[row * DN + lane];
    float f1 = src[row * DN + 64 + lane];
    float ss = f0 * f0 + f1 * f1;
    #pragma unroll
    for (int o = 32; o > 0; o >>= 1) ss += __shfl_xor(ss, o);
    float inv = 1.0f / fmaxf(sqrtf(ss), 1e-12f);
    dst[row * DN + lane] = f0 * inv;
    dst[row * DN + 64 + lane] = f1 * inv;
    if (lane == 0) sq[row] = raw_sq ? ss : ss * inv * inv;
}

__global__ void hist_kernel(const int* __restrict__ labels, int* __restrict__ counts) {
    int i = blockIdx.x * 256 + threadIdx.x;
    atomicAdd(&counts[labels[i]], 1);
}

// stage a 64-row x 128-col fp32 tile into LDS, XOR-swizzled float4 chunks:
// element (r, chunk c4) stored at sT[r*32 + (c4 ^ (r&7))]. Zero-pad rows >= nmax.
__device__ __forceinline__ void stage_tile(float4* sT, const float* __restrict__ src,
                                           int row0, int nmax, int tid) {
    const float4* sv = (const float4*)src;
    #pragma unroll
    for (int s = 0; s < 8; s++) {
        int c = tid + s * 256;
        int r = c >> 5, c4 = c & 31;
        int row = row0 + r;
        float4 v;
        if (row < nmax) v = sv[row * 32 + c4];
        else v = make_float4(0.f, 0.f, 0.f, 0.f);
        sT[r * 32 + (c4 ^ (r & 7))] = v;
    }
}

// -------- neg_sqr_dist: 64x64 tile GEMM (feat_n x means^T) + epilogue --------
__global__ __launch_bounds__(256) void nsd_kernel(const float* __restrict__ featn,
        const float* __restrict__ means, const float* __restrict__ xx,
        const float* __restrict__ yy, float* __restrict__ out) {
    __shared__ float4 sA[64 * 32];
    __shared__ float4 sB[64 * 32];
    int tid = threadIdx.x;
    int i0 = blockIdx.y * 64;
    int j0 = blockIdx.x * 64;
    stage_tile(sA, featn, i0, BN, tid);
    stage_tile(sB, means, j0, CN, tid);
    __syncthreads();
    int tx = tid & 15, ty = tid >> 4;
    int ma = ty & 7, mb = tx & 7;
    float acc[4][4];
    #pragma unroll
    for (int ii = 0; ii < 4; ii++)
        #pragma unroll
        for (int jj = 0; jj < 4; jj++) acc[ii][jj] = 0.f;
    #pragma unroll 4
    for (int k4 = 0; k4 < 32; k4++) {
        float4 av[4], bv[4];
        #pragma unroll
        for (int ii = 0; ii < 4; ii++) av[ii] = sA[(ty + 16 * ii) * 32 + (k4 ^ ma)];
        #pragma unroll
        for (int jj = 0; jj < 4; jj++) bv[jj] = sB[(tx + 16 * jj) * 32 + (k4 ^ mb)];
        #pragma unroll
        for (int ii = 0; ii < 4; ii++)
            #pragma unroll
            for (int jj = 0; jj < 4; jj++)
                acc[ii][jj] += av[ii].x * bv[jj].x + av[ii].y * bv[jj].y +
                               av[ii].z * bv[jj].z + av[ii].w * bv[jj].w;
    }
    int jg[4]; float yyv[4];
    #pragma unroll
    for (int jj = 0; jj < 4; jj++) {
        jg[jj] = j0 + tx + 16 * jj;
        yyv[jj] = (jg[jj] < CN) ? yy[jg[jj]] : 0.f;
    }
    #pragma unroll
    for (int ii = 0; ii < 4; ii++) {
        int ig = i0 + ty + 16 * ii;
        float xv = xx[ig];
        #pragma unroll
        for (int jj = 0; jj < 4; jj++)
            if (jg[jj] < CN)
                out[ig * CN + jg[jj]] = -0.5f * (xv - 2.f * acc[ii][jj] + yyv[jj]);
    }
}

// -------- CE: one block per row, logsumexp over 1000 margin-scaled logits --------
__global__ __launch_bounds__(256) void ce_kernel(const float* __restrict__ nsd,
        const int* __restrict__ labels, float* __restrict__ ce_sum) {
    int row = blockIdx.x, tid = threadIdx.x;
    int label = labels[row];
    const float* r = nsd + (long)row * CN;
    __shared__ float red[4];
    __shared__ float labv;
    float v[4]; float mx = -INFINITY;
    #pragma unroll
    for (int s = 0; s < 4; s++) {
        int j = tid + 256 * s;
        if (j < CN) {
            float l = r[j] * ((j == label) ? 1.5f : 1.0f);
            v[s] = l;
            mx = fmaxf(mx, l);
            if (j == label) labv = l;
        } else v[s] = -INFINITY;
    }
    #pragma unroll
    for (int o = 32; o > 0; o >>= 1) mx = fmaxf(mx, __shfl_xor(mx, o));
    int w = tid >> 6, lane = tid & 63;
    if (lane == 0) red[w] = mx;
    __syncthreads();
    float M = fmaxf(fmaxf(red[0], red[1]), fmaxf(red[2], red[3]));
    float e = 0.f;
    #pragma unroll
    for (int s = 0; s < 4; s++) e += __expf(v[s] - M);
    #pragma unroll
    for (int o = 32; o > 0; o >>= 1) e += __shfl_xor(e, o);
    __syncthreads();
    if (lane == 0) red[w] = e;
    __syncthreads();
    if (tid == 0) {
        float S = red[0] + red[1] + red[2] + red[3];
        atomicAdd(ce_sum, (M + logf(S)) - labv);
    }
}

__global__ void margin_kernel(const float* __restrict__ featn, const float* __restrict__ meansn,
                              const int* __restrict__ labels, float* __restrict__ msum) {
    int row = blockIdx.x * 4 + (threadIdx.x >> 6);
    int lane = threadIdx.x & 63;
    int lab = labels[row];
    float d0 = featn[row * DN + lane] - meansn[lab * DN + lane];
    float d1 = featn[row * DN + 64 + lane] - meansn[lab * DN + 64 + lane];
    float ss = d0 * d0 + d1 * d1;
    #pragma unroll
    for (int o = 32; o > 0; o >>= 1) ss += __shfl_xor(ss, o);
    if (lane == 0) atomicAdd(msum, ss);
}

// -------- SCL core: 64x64 tiles of sim = feat_n feat_n^T / T, accumulate
// bottom_i = sum_{j!=i} exp(sim), pos_i = sum_{same label, j!=i} sim --------
__global__ __launch_bounds__(256) void scl_kernel(const float* __restrict__ featn,
        const int* __restrict__ labels, float* __restrict__ bottom, float* __restrict__ pos) {
    __shared__ float4 sA[64 * 32];
    __shared__ float4 sB[64 * 32];
    int tid = threadIdx.x;
    int i0 = blockIdx.y * 64;
    int jstrip = blockIdx.x;          // 0..3, each covers 2048 j
    stage_tile(sA, featn, i0, BN, tid);
    int tx = tid & 15, ty = tid >> 4;
    int ma = ty & 7, mb = tx & 7;
    int ig[4], labi[4];
    float bs[4] = {0.f, 0.f, 0.f, 0.f}, ps[4] = {0.f, 0.f, 0.f, 0.f};
    #pragma unroll
    for (int ii = 0; ii < 4; ii++) {
        ig[ii] = i0 + ty + 16 * ii;
        labi[ii] = labels[ig[ii]];
    }
    for (int t = 0; t < 32; t++) {
        int j0 = jstrip * 2048 + t * 64;
        __syncthreads();              // protect sB from previous-iter readers (covers sA at t=0)
        stage_tile(sB, featn, j0, BN, tid);
        __syncthreads();
        float acc[4][4];
        #pragma unroll
        for (int ii = 0; ii < 4; ii++)
            #pragma unroll
            for (int jj = 0; jj < 4; jj++) acc[ii][jj] = 0.f;
        #pragma unroll 4
        for (int k4 = 0; k4 < 32; k4++) {
            float4 av[4], bv[4];
            #pragma unroll
            for (int ii = 0; ii < 4; ii++) av[ii] = sA[(ty + 16 * ii) * 32 + (k4 ^ ma)];
            #pragma unroll
            for (int jj = 0; jj < 4; jj++) bv[jj] = sB[(tx + 16 * jj) * 32 + (k4 ^ mb)];
            #pragma unroll
            for (int ii = 0; ii < 4; ii++)
                #pragma unroll
                for (int jj = 0; jj < 4; jj++)
                    acc[ii][jj] += av[ii].x * bv[jj].x + av[ii].y * bv[jj].y +
                                   av[ii].z * bv[jj].z + av[ii].w * bv[jj].w;
        }
        int jg[4], labj[4];
        #pragma unroll
        for (int jj = 0; jj < 4; jj++) {
            jg[jj] = j0 + tx + 16 * jj;
            labj[jj] = labels[jg[jj]];
        }
        #pragma unroll
        for (int ii = 0; ii < 4; ii++)
            #pragma unroll
            for (int jj = 0; jj < 4; jj++) {
                float sim = acc[ii][jj] * INVT;
                if (jg[jj] != ig[ii]) {
                    bs[ii] += __expf(sim);
                    if (labj[jj] == labi[ii]) ps[ii] += sim;
                }
            }
    }
    #pragma unroll
    for (int ii = 0; ii < 4; ii++) {
        float b = bs[ii], p = ps[ii];
        #pragma unroll
        for (int o = 8; o > 0; o >>= 1) {   // reduce across the 16 tx lanes
            b += __shfl_xor(b, o);
            p += __shfl_xor(p, o);
        }
        if (tx == 0) {
            atomicAdd(&bottom[ig[ii]], b);
            atomicAdd(&pos[ig[ii]], p);
        }
    }
}

__global__ void final_kernel(const float* __restrict__ bottom, const float* __restrict__ pos,
        const int* __restrict__ labels, const int* __restrict__ counts,
        const float* __restrict__ ce_sum, const float* __restrict__ m_sum,
        float* __restrict__ loss_out) {
    int tid = threadIdx.x;
    float sp = 0.f; float nv = 0.f;
    for (int i = tid; i < BN; i += 256) {
        int c = counts[labels[i]] - 1;
        if (c > 0) {
            sp += pos[i] / (float)c - logf(bottom[i]);
            nv += 1.f;
        }
    }
    #pragma unroll
    for (int o = 32; o > 0; o >>= 1) {
        sp += __shfl_xor(sp, o);
        nv += __shfl_xor(nv, o);
    }
    __shared__ float r1[4], r2[4];
    int w = tid >> 6, lane = tid & 63;
    if (lane == 0) { r1[w] = sp; r2[w] = nv; }
    __syncthreads();
    if (tid == 0) {
        float SP = r1[0] + r1[1] + r1[2] + r1[3];
        float NV = r2[0] + r2[1] + r2[2] + r2[3];
        float scl = -SP / fmaxf(NV, 1.f);
        float ce = ce_sum[0] / (float)BN;
        float mg = m_sum[0] / (2.f * (float)BN);
        loss_out[0] = 0.9f * ce + 0.1f * scl + 0.5f * mg;
    }
}

extern "C" void kernel_launch(void* const* d_in, const int* in_sizes, int n_in,
                              void* d_out, int out_size, void* d_ws, size_t ws_size,
                              hipStream_t stream) {
    const float* feat  = (const float*)d_in[0];
    const int*   labels = (const int*)d_in[1];
    const float* means = (const float*)d_in[2];
    float* out = (float*)d_out;
    float* ws  = (float*)d_ws;

    float* featn  = ws + F_FEATN;
    float* xx     = ws + F_XX;
    float* meansn = ws + F_MEANSN;
    float* yy     = ws + F_YY;
    float* bottom = ws + F_BOT;
    float* pos    = ws + F_POS;
    int*   counts = (int*)(ws + F_CNT);
    float* ce_sum = ws + F_CE;
    float* m_sum  = ws + F_MG;

    // zero all accumulators (ws is poisoned 0xAA before every launch)
    hipMemsetAsync(ws + F_BOT, 0, (size_t)(8192 + 8192 + 1000 + 2) * sizeof(float), stream);

    norm_rows<<<2048, 256, 0, stream>>>(feat, featn, xx, BN, 0);
    norm_rows<<<250, 256, 0, stream>>>(means, meansn, yy, CN, 1);
    hist_kernel<<<32, 256, 0, stream>>>(labels, counts);
    nsd_kernel<<<dim3(16, 128), 256, 0, stream>>>(featn, means, xx, yy, out);
    ce_kernel<<<8192, 256, 0, stream>>>(out, labels, ce_sum);
    margin_kernel<<<2048, 256, 0, stream>>>(featn, meansn, labels, m_sum);
    scl_kernel<<<dim3(4, 128), 256, 0, stream>>>(featn, labels, bottom, pos);
    final_kernel<<<1, 256, 0, stream>>>(bottom, pos, labels, counts, ce_sum, m_sum,
                                        out + (long)BN * CN);
}

// Round 2
// 175.992 us; speedup vs baseline: 3.9766x; 3.9766x over previous
//
#include <hip/hip_runtime.h>
#include <math.h>

#define BN 8192
#define CN 1000
#define DN 128
#define INVT (1.0f/0.3f)

typedef __bf16 bf16x8 __attribute__((ext_vector_type(8)));
typedef float  f32x4  __attribute__((ext_vector_type(4)));

// ws layout in floats
#define F_FEATN  0          // 8192*128 fp32 (for margin)
#define F_MEANSN 1048576    // 1000*128 fp32 normalized (for margin)
#define F_XX     1176576    // 8192
#define F_YY     1184768    // 1000
#define F_FEATB  1185768    // 8192*128 bf16 = 524288 floats
#define F_MEANSB 1710056    // 1024*128 bf16 (raw means, zero-padded rows 1000..1023)
#define F_CEROW  1775592    // 8192
#define F_MROW   1783784    // 8192
#define F_BOT    1791976    // 8192   -- zeroed region start
#define F_POS    1800168    // 8192
#define F_CNT    1808360    // 1000 ints

// -------- row L2-normalize. Writes fp32 normalized + optional bf16 normalized.
// raw_sq=1 -> sq = ||row||^2 pre-norm (YY); raw_sq=0 -> sq of normalized row (XX).
__global__ void norm_rows(const float* __restrict__ src, float* __restrict__ dst,
                          float* __restrict__ sq, __bf16* __restrict__ dstb,
                          int nrows, int raw_sq) {
    int row = blockIdx.x * 4 + (threadIdx.x >> 6);
    if (row >= nrows) return;
    int lane = threadIdx.x & 63;
    float f0 = src[row * DN + lane];
    float f1 = src[row * DN + 64 + lane];
    float ss = f0 * f0 + f1 * f1;
    #pragma unroll
    for (int o = 32; o > 0; o >>= 1) ss += __shfl_xor(ss, o);
    float inv = 1.0f / fmaxf(sqrtf(ss), 1e-12f);
    float n0 = f0 * inv, n1 = f1 * inv;
    dst[row * DN + lane] = n0;
    dst[row * DN + 64 + lane] = n1;
    if (dstb) {
        dstb[row * DN + lane] = (__bf16)n0;
        dstb[row * DN + 64 + lane] = (__bf16)n1;
    }
    if (lane == 0) sq[row] = raw_sq ? ss : ss * inv * inv;
}

// raw means -> bf16, zero-pad rows [nrows_src, 1024)
__global__ void to_bf16_pad(const float* __restrict__ src, __bf16* __restrict__ dst,
                            int nrows_src) {
    int idx = blockIdx.x * 256 + threadIdx.x;     // 1024*128 total
    int row = idx >> 7;
    dst[idx] = (__bf16)((row < nrows_src) ? src[idx] : 0.f);
}

__global__ void hist_kernel(const int* __restrict__ labels, int* __restrict__ counts) {
    int i = blockIdx.x * 256 + threadIdx.x;
    atomicAdd(&counts[labels[i]], 1);
}

// stage a 128x128 bf16 tile (32 KB) into LDS as XOR-swizzled 16B chunks:
// chunk (r, ch) -> sT[r*16 + (ch ^ (r&7))]
__device__ __forceinline__ void stage128(uint4* sT, const uint4* __restrict__ src,
                                         int row0, int tid) {
    #pragma unroll
    for (int s = 0; s < 8; s++) {
        int c = tid + s * 256;
        int r = c >> 4, ch = c & 15;
        sT[r * 16 + (ch ^ (r & 7))] = src[(size_t)(row0 + r) * 16 + ch];
    }
}

// -------- neg_sqr_dist: 128x128 MFMA tile, B = raw means (padded to 1024 rows) --------
__global__ __launch_bounds__(256, 2) void nsd_kernel(const __bf16* __restrict__ featb,
        const __bf16* __restrict__ meansb, const float* __restrict__ xx,
        const float* __restrict__ yy, float* __restrict__ out) {
    __shared__ uint4 sA[2048];
    __shared__ uint4 sB[2048];
    int tid = threadIdx.x;
    int i0 = blockIdx.y * 128, j0 = blockIdx.x * 128;
    stage128(sA, (const uint4*)featb, i0, tid);
    stage128(sB, (const uint4*)meansb, j0, tid);
    __syncthreads();
    int lane = tid & 63, w = tid >> 6;
    int wrow = (w >> 1) * 64, wcol = (w & 1) * 64;
    int q = lane >> 4, l15 = lane & 15;
    int ibase = i0 + wrow + q * 4;

    f32x4 acc[4][4];
    #pragma unroll
    for (int ii = 0; ii < 4; ii++)
        #pragma unroll
        for (int jj = 0; jj < 4; jj++) acc[ii][jj] = (f32x4){0.f, 0.f, 0.f, 0.f};
    #pragma unroll
    for (int kk = 0; kk < 4; kk++) {
        bf16x8 af[4], bfv[4];
        #pragma unroll
        for (int ii = 0; ii < 4; ii++) {
            int r = wrow + ii * 16 + l15;
            af[ii] = *(const bf16x8*)&sA[r * 16 + ((kk * 4 + q) ^ (r & 7))];
        }
        #pragma unroll
        for (int jj = 0; jj < 4; jj++) {
            int r = wcol + jj * 16 + l15;
            bfv[jj] = *(const bf16x8*)&sB[r * 16 + ((kk * 4 + q) ^ (r & 7))];
        }
        #pragma unroll
        for (int ii = 0; ii < 4; ii++)
            #pragma unroll
            for (int jj = 0; jj < 4; jj++)
                acc[ii][jj] = __builtin_amdgcn_mfma_f32_16x16x32_bf16(
                    af[ii], bfv[jj], acc[ii][jj], 0, 0, 0);
    }
    int jg[4]; float yv[4];
    #pragma unroll
    for (int jj = 0; jj < 4; jj++) {
        jg[jj] = j0 + wcol + jj * 16 + l15;
        yv[jj] = (jg[jj] < CN) ? yy[jg[jj]] : 0.f;
    }
    #pragma unroll
    for (int ii = 0; ii < 4; ii++) {
        float4 xv = ((const float4*)xx)[(ibase + ii * 16) >> 2];
        float xa[4] = {xv.x, xv.y, xv.z, xv.w};
        #pragma unroll
        for (int r4 = 0; r4 < 4; r4++) {
            int ig = ibase + ii * 16 + r4;
            #pragma unroll
            for (int jj = 0; jj < 4; jj++)
                if (jg[jj] < CN)
                    out[(size_t)ig * CN + jg[jj]] =
                        -0.5f * (xa[r4] - 2.f * acc[ii][jj][r4] + yv[jj]);
        }
    }
}

// -------- CE: one block per row, logsumexp over 1000 margin-scaled logits --------
__global__ __launch_bounds__(256) void ce_kernel(const float* __restrict__ nsd,
        const int* __restrict__ labels, float* __restrict__ ce_row) {
    int row = blockIdx.x, tid = threadIdx.x;
    int label = labels[row];
    const float* r = nsd + (size_t)row * CN;
    __shared__ float red[4];
    __shared__ float labv;
    float v[4]; float mx = -INFINITY;
    #pragma unroll
    for (int s = 0; s < 4; s++) {
        int j = tid + 256 * s;
        if (j < CN) {
            float l = r[j] * ((j == label) ? 1.5f : 1.0f);
            v[s] = l;
            mx = fmaxf(mx, l);
            if (j == label) labv = l;
        } else v[s] = -INFINITY;
    }
    #pragma unroll
    for (int o = 32; o > 0; o >>= 1) mx = fmaxf(mx, __shfl_xor(mx, o));
    int w = tid >> 6, lane = tid & 63;
    if (lane == 0) red[w] = mx;
    __syncthreads();
    float M = fmaxf(fmaxf(red[0], red[1]), fmaxf(red[2], red[3]));
    float e = 0.f;
    #pragma unroll
    for (int s = 0; s < 4; s++) e += __expf(v[s] - M);
    #pragma unroll
    for (int o = 32; o > 0; o >>= 1) e += __shfl_xor(e, o);
    __syncthreads();
    if (lane == 0) red[w] = e;
    __syncthreads();
    if (tid == 0) {
        float S = red[0] + red[1] + red[2] + red[3];
        ce_row[row] = (M + logf(S)) - labv;
    }
}

__global__ void margin_kernel(const float* __restrict__ featn, const float* __restrict__ meansn,
                              const int* __restrict__ labels, float* __restrict__ m_row) {
    int row = blockIdx.x * 4 + (threadIdx.x >> 6);
    int lane = threadIdx.x & 63;
    int lab = labels[row];
    float d0 = featn[row * DN + lane] - meansn[lab * DN + lane];
    float d1 = featn[row * DN + 64 + lane] - meansn[lab * DN + 64 + lane];
    float ss = d0 * d0 + d1 * d1;
    #pragma unroll
    for (int o = 32; o > 0; o >>= 1) ss += __shfl_xor(ss, o);
    if (lane == 0) m_row[row] = ss;
}

// -------- SCL core: 128x128 MFMA tiles of sim = F F^T / T.
// Each block: one 128-row i-block x 8 j-tiles (1024 cols). Accumulate
// bottom_i = sum_{j!=i} exp(sim), pos_i = sum_{same-label, j!=i} sim in regs,
// reduce across the 16 col-lanes, atomicAdd once per row at the end. --------
__global__ __launch_bounds__(256, 2) void scl_kernel(const __bf16* __restrict__ featb,
        const int* __restrict__ labels, float* __restrict__ bottom, float* __restrict__ pos) {
    __shared__ uint4 sA[2048];
    __shared__ uint4 sB[2048];
    int tid = threadIdx.x;
    int i0 = blockIdx.y * 128;
    int jstrip = blockIdx.x;   // 0..7, each covers 1024 cols
    const uint4* fv = (const uint4*)featb;
    stage128(sA, fv, i0, tid);

    int lane = tid & 63, w = tid >> 6;
    int wrow = (w >> 1) * 64, wcol = (w & 1) * 64;
    int q = lane >> 4, l15 = lane & 15;
    int ibase = i0 + wrow + q * 4;

    int labi[4][4];
    #pragma unroll
    for (int ii = 0; ii < 4; ii++) {
        int4 lv = ((const int4*)labels)[(ibase + ii * 16) >> 2];
        labi[ii][0] = lv.x; labi[ii][1] = lv.y; labi[ii][2] = lv.z; labi[ii][3] = lv.w;
    }
    float bs[4][4] = {}, ps[4][4] = {};

    for (int t = 0; t < 8; t++) {
        int j0 = jstrip * 1024 + t * 128;
        __syncthreads();               // prior sB readers done (covers sA stage at t=0)
        stage128(sB, fv, j0, tid);
        __syncthreads();

        f32x4 acc[4][4];
        #pragma unroll
        for (int ii = 0; ii < 4; ii++)
            #pragma unroll
            for (int jj = 0; jj < 4; jj++) acc[ii][jj] = (f32x4){0.f, 0.f, 0.f, 0.f};
        #pragma unroll
        for (int kk = 0; kk < 4; kk++) {
            bf16x8 af[4], bfv[4];
            #pragma unroll
            for (int ii = 0; ii < 4; ii++) {
                int r = wrow + ii * 16 + l15;
                af[ii] = *(const bf16x8*)&sA[r * 16 + ((kk * 4 + q) ^ (r & 7))];
            }
            #pragma unroll
            for (int jj = 0; jj < 4; jj++) {
                int r = wcol + jj * 16 + l15;
                bfv[jj] = *(const bf16x8*)&sB[r * 16 + ((kk * 4 + q) ^ (r & 7))];
            }
            #pragma unroll
            for (int ii = 0; ii < 4; ii++)
                #pragma unroll
                for (int jj = 0; jj < 4; jj++)
                    acc[ii][jj] = __builtin_amdgcn_mfma_f32_16x16x32_bf16(
                        af[ii], bfv[jj], acc[ii][jj], 0, 0, 0);
        }

        int labj[4], jg[4];
        #pragma unroll
        for (int jj = 0; jj < 4; jj++) {
            jg[jj] = j0 + wcol + jj * 16 + l15;
            labj[jj] = labels[jg[jj]];
        }
        #pragma unroll
        for (int ii = 0; ii < 4; ii++)
            #pragma unroll
            for (int jj = 0; jj < 4; jj++)
                #pragma unroll
                for (int r4 = 0; r4 < 4; r4++) {
                    float sim = acc[ii][jj][r4] * INVT;
                    int ig = ibase + ii * 16 + r4;
                    bool off = (ig != jg[jj]);
                    float e = __expf(sim);
                    bs[ii][r4] += off ? e : 0.f;
                    ps[ii][r4] += (off && labj[jj] == labi[ii][r4]) ? sim : 0.f;
                }
    }

    #pragma unroll
    for (int ii = 0; ii < 4; ii++)
        #pragma unroll
        for (int r4 = 0; r4 < 4; r4++) {
            float b = bs[ii][r4], p = ps[ii][r4];
            #pragma unroll
            for (int o = 8; o > 0; o >>= 1) {   // reduce the 16 col-lanes
                b += __shfl_xor(b, o);
                p += __shfl_xor(p, o);
            }
            if (l15 == 0) {
                atomicAdd(&bottom[ibase + ii * 16 + r4], b);
                atomicAdd(&pos[ibase + ii * 16 + r4], p);
            }
        }
}

__global__ void final_kernel(const float* __restrict__ bottom, const float* __restrict__ pos,
        const int* __restrict__ labels, const int* __restrict__ counts,
        const float* __restrict__ ce_row, const float* __restrict__ m_row,
        float* __restrict__ loss_out) {
    int tid = threadIdx.x;
    float sp = 0.f, nv = 0.f, ce = 0.f, mg = 0.f;
    for (int i = tid; i < BN; i += 256) {
        ce += ce_row[i];
        mg += m_row[i];
        int c = counts[labels[i]] - 1;
        if (c > 0) {
            sp += pos[i] / (float)c - logf(bottom[i]);
            nv += 1.f;
        }
    }
    #pragma unroll
    for (int o = 32; o > 0; o >>= 1) {
        sp += __shfl_xor(sp, o);
        nv += __shfl_xor(nv, o);
        ce += __shfl_xor(ce, o);
        mg += __shfl_xor(mg, o);
    }
    __shared__ float r1[4], r2[4], r3[4], r4[4];
    int w = tid >> 6, lane = tid & 63;
    if (lane == 0) { r1[w] = sp; r2[w] = nv; r3[w] = ce; r4[w] = mg; }
    __syncthreads();
    if (tid == 0) {
        float SP = r1[0] + r1[1] + r1[2] + r1[3];
        float NV = r2[0] + r2[1] + r2[2] + r2[3];
        float CE = r3[0] + r3[1] + r3[2] + r3[3];
        float MG = r4[0] + r4[1] + r4[2] + r4[3];
        float scl = -SP / fmaxf(NV, 1.f);
        loss_out[0] = 0.9f * (CE / (float)BN) + 0.1f * scl + 0.5f * (MG / (2.f * (float)BN));
    }
}

extern "C" void kernel_launch(void* const* d_in, const int* in_sizes, int n_in,
                              void* d_out, int out_size, void* d_ws, size_t ws_size,
                              hipStream_t stream) {
    const float* feat   = (const float*)d_in[0];
    const int*   labels = (const int*)d_in[1];
    const float* means  = (const float*)d_in[2];
    float* out = (float*)d_out;
    float* ws  = (float*)d_ws;

    float*  featn  = ws + F_FEATN;
    float*  meansn = ws + F_MEANSN;
    float*  xx     = ws + F_XX;
    float*  yy     = ws + F_YY;
    __bf16* featb  = (__bf16*)(ws + F_FEATB);
    __bf16* meansb = (__bf16*)(ws + F_MEANSB);
    float*  ce_row = ws + F_CEROW;
    float*  m_row  = ws + F_MROW;
    float*  bottom = ws + F_BOT;
    float*  pos    = ws + F_POS;
    int*    counts = (int*)(ws + F_CNT);

    // zero accumulators (ws is re-poisoned 0xAA before every launch)
    hipMemsetAsync(ws + F_BOT, 0, (size_t)(8192 + 8192 + 1000) * sizeof(float), stream);

    norm_rows<<<2048, 256, 0, stream>>>(feat, featn, xx, featb, BN, 0);
    norm_rows<<<250, 256, 0, stream>>>(means, meansn, yy, nullptr, CN, 1);
    to_bf16_pad<<<512, 256, 0, stream>>>(means, meansb, CN);
    hist_kernel<<<32, 256, 0, stream>>>(labels, counts);
    nsd_kernel<<<dim3(8, 64), 256, 0, stream>>>(featb, meansb, xx, yy, out);
    ce_kernel<<<8192, 256, 0, stream>>>(out, labels, ce_row);
    margin_kernel<<<2048, 256, 0, stream>>>(featn, meansn, labels, m_row);
    scl_kernel<<<dim3(8, 64), 256, 0, stream>>>(featb, labels, bottom, pos);
    final_kernel<<<1, 256, 0, stream>>>(bottom, pos, labels, counts, ce_row, m_row,
                                        out + (size_t)BN * CN);
}